// Round 12
// baseline (343.209 us; speedup 1.0000x reference)
//
#include <hip/hip_runtime.h>
#include <hip/hip_bf16.h>
#include <float.h>

// z: (64, 256, 32, 32) fp32 ; emb: (1024, 256) fp32
// M = 65536 pixels, D = 256, K = 1024 codes
// out: [z_q (16777216 f)] [indices as float (65536)] [vq_loss (1)]
#define OUT_IDX_OFF 16777216
#define OUT_LOSS_OFF 16842752
// Fallback scratch inside d_out's z_q region (overwritten by k_out at end):
#define CAND_OFF 8388608
#define GMIN_OFF 12582912
#define GCNT_OFF 13107200
#define NSLOT 32
#define DELTA 2.0e-3f

typedef __attribute__((ext_vector_type(8))) short short8;
typedef __attribute__((ext_vector_type(4))) float f32x4;

static __device__ __forceinline__ unsigned short f2bf(float f) {
  union { __hip_bfloat16 h; unsigned short u; } cv;
  cv.h = __float2bfloat16(f);
  return cv.u;
}

// ---------------------------------------------------------------------------
// P1: emb -> E2 bf16 [1024 codes][256 d] row-major + exact cws (proven).
// Also absorbs the three memsets (gmin=+inf pattern, gcnt=0, loss=0).
// ---------------------------------------------------------------------------
__global__ __launch_bounds__(256) void k_prep(const float* __restrict__ emb,
                                              unsigned short* __restrict__ E2,
                                              float* __restrict__ cws,
                                              int* __restrict__ gmin,
                                              int* __restrict__ gcnt,
                                              float* __restrict__ out) {
  const int k = blockIdx.x, d = threadIdx.x;
  const int tid = (k << 8) + d;
  if (tid < 65536) {
    gmin[tid] = 0x7f7f7f7f;  // ~ +inf (same pattern as old memset)
    gcnt[tid] = 0;
  }
  if (tid == 0) out[OUT_LOSS_OFF] = 0.0f;
  const float v = emb[k * 256 + d];
  __shared__ float red[256];
  __shared__ unsigned short row[256];
  row[d] = f2bf(v);
  red[d] = v * v;
  __syncthreads();
  for (int s = 128; s > 0; s >>= 1) {
    if (d < s) red[d] += red[d + s];
    __syncthreads();
  }
  if (d == 0) cws[k] = red[0];
  if (d < 32) ((short8*)&E2[k * 256])[d] = ((short8*)row)[d];
}

// ---------------------------------------------------------------------------
// k_cvt4: FUSED z->A2 bf16 (row-major) + exact aws (k_a absorbed). Proven.
// ---------------------------------------------------------------------------
__global__ __launch_bounds__(256) void k_cvt4(const float* __restrict__ z,
                                              unsigned short* __restrict__ A2,
                                              float* __restrict__ aws) {
#pragma clang fp contract(off)
  __shared__ float tile[64][65];
  __shared__ float red2[128];
  const int t = threadIdx.x;
  const int p0 = blockIdx.x << 6;
  const int n = p0 >> 10, hw0 = p0 & 1023;
  const float* zb = z + (size_t)n * 262144 + hw0;
  const int hwl = (t & 15) << 2;
  const int dlb = t >> 4;  // 0..15
  const int row = t & 63, h = (t >> 6) & 1;  // acc assignment (t<128)
  const int pl = t >> 2, c = t & 3;          // A2-store assignment

  float4 v[4];
#pragma unroll
  for (int i = 0; i < 4; ++i)
    v[i] = *(const float4*)&zb[(size_t)(dlb + i * 16) * 1024 + hwl];

  float acc[8];

  for (int dt = 0; dt < 4; ++dt) {
    if (dt) __syncthreads();  // previous-phase readers done
#pragma unroll
    for (int i = 0; i < 4; ++i) {
      const int dl = dlb + i * 16;
      tile[hwl + 0][dl] = v[i].x;
      tile[hwl + 1][dl] = v[i].y;
      tile[hwl + 2][dl] = v[i].z;
      tile[hwl + 3][dl] = v[i].w;
    }
    __syncthreads();
    if (dt < 3) {  // prefetch next slab into regs (overlaps phase below)
      const float* zb2 = zb + (size_t)(dt + 1) * 65536;
#pragma unroll
      for (int i = 0; i < 4; ++i)
        v[i] = *(const float4*)&zb2[(size_t)(dlb + i * 16) * 1024 + hwl];
    }
    // A2 store (verbatim k_cvt2 store phase, d0 = dt*64)
    unsigned short* dst = &A2[(size_t)(p0 + pl) * 256 + dt * 64];
#pragma unroll
    for (int hh = 0; hh < 2; ++hh) {
      const int ch = c + hh * 4;
      unsigned short tmp[8];
#pragma unroll
      for (int j = 0; j < 8; ++j) tmp[j] = f2bf(tile[pl][ch * 8 + j]);
      *(short8*)&dst[ch * 8] = *(short8*)tmp;
    }
    // aws chain: wave0 (h=0) consumes slabs 0,1; wave1 (h=1) slabs 2,3
    if (t < 128 && (dt >> 1) == h) {
      if ((dt & 1) == 0) {
#pragma unroll
        for (int j = 0; j < 8; ++j) {
          const float x = tile[row][j];
          acc[j] = x * x;  // g = 0 init
        }
        for (int g = 1; g < 8; ++g)
#pragma unroll
          for (int j = 0; j < 8; ++j) {
            const float x = tile[row][g * 8 + j];
            const float p = x * x;
            acc[j] = acc[j] + p;
          }
      } else {
        for (int g = 8; g < 16; ++g)
#pragma unroll
          for (int j = 0; j < 8; ++j) {
            const float x = tile[row][(g - 8) * 8 + j];
            const float p = x * x;
            acc[j] = acc[j] + p;
          }
      }
    }
  }
  if (t < 128) {
    const float s = ((acc[0] + acc[1]) + (acc[2] + acc[3])) +
                    ((acc[4] + acc[5]) + (acc[6] + acc[7]));
    red2[t] = s;
  }
  __syncthreads();
  if (t < 64) aws[p0 + t] = red2[t] + red2[t + 64];  // fl(s_h0 + s_h1), as k_a
}

// ---------------------------------------------------------------------------
// k_gemm9: VERBATIM R2 k_gemm4 (proven 96.5/96.0/99us across R2/R7/R9).
// This 128x128 shape is the measured optimum of the stage->drain->compute
// structure (R10 falsified the occupancy-first model); do not re-tune.
// ---------------------------------------------------------------------------
__global__ __launch_bounds__(256, 4) void k_gemm9(
    const unsigned short* __restrict__ A2, const unsigned short* __restrict__ E2,
    const float* __restrict__ cws, const float* __restrict__ aws,
    int* __restrict__ gmin, int* __restrict__ gcnt,
    float2* __restrict__ gcand) {
  __shared__ __align__(16) unsigned short As[128 * 64];
  __shared__ __align__(16) unsigned short Bs[128 * 64];
  __shared__ float a_l[128], c_l[128], rmkt[256], bmin[128];

  const int t = threadIdx.x;
  const int lane = t & 63;
  const int wave = __builtin_amdgcn_readfirstlane(t >> 6);
  const int wr = wave >> 1, wc = wave & 1;
  const int quad = lane >> 4, l15 = lane & 15;
  const int swa = l15 & 7;

  // XCD-chunked swizzle (grid 4096 % 8 == 0 -> bijective)
  const int bid = blockIdx.x;
  const int L = ((bid & 7) << 9) + (bid >> 3);
  const int rb = L >> 3, ck = L & 7;
  const int r0 = rb << 7, k0 = ck << 7;

  if (t < 128) {
    a_l[t] = aws[r0 + t];
    c_l[t] = cws[k0 + t];
  }

  // staging geometry: round i covers 16B-granules G = i*256 + t of the
  // [128 rows][8 granules] kt-tile; row = G>>3, physical granule gpos = G&7,
  // source granule gpos^(row&7) (involution; matches fragment-read swizzle).
  const int srow = t >> 3;  // rows advance by 32 per round
  const int gpos = t & 7;

  f32x4 acc[4][4];
#pragma unroll
  for (int a = 0; a < 4; ++a)
#pragma unroll
    for (int b = 0; b < 4; ++b) acc[a][b] = (f32x4)(0.0f);

  for (int kt = 0; kt < 4; ++kt) {
    if (kt) __syncthreads();  // waves done reading previous tiles
#pragma unroll
    for (int i = 0; i < 4; ++i) {
      const int row = (i << 5) + srow;
      const int gsrc = gpos ^ (row & 7);
      const unsigned short* sa =
          A2 + (((size_t)(r0 + row)) << 8) + (kt << 6) + (gsrc << 3);
      __builtin_amdgcn_global_load_lds(
          (const __attribute__((address_space(1))) void*)sa,
          (__attribute__((address_space(3))) void*)(As + (i << 11) +
                                                    (wave << 9)),
          16, 0, 0);
      const unsigned short* sb =
          E2 + (((size_t)(k0 + row)) << 8) + (kt << 6) + (gsrc << 3);
      __builtin_amdgcn_global_load_lds(
          (const __attribute__((address_space(1))) void*)sb,
          (__attribute__((address_space(3))) void*)(Bs + (i << 11) +
                                                    (wave << 9)),
          16, 0, 0);
    }
    __syncthreads();  // vmcnt drained -> tiles ready
#pragma unroll
    for (int ks = 0; ks < 2; ++ks) {
      short8 af[4], bf[4];
#pragma unroll
      for (int tr = 0; tr < 4; ++tr)
        af[tr] = *(const short8*)&As[(wr * 64 + tr * 16 + l15) * 64 +
                                     (((ks * 4 + quad) ^ swa) << 3)];
#pragma unroll
      for (int tc = 0; tc < 4; ++tc)
        bf[tc] = *(const short8*)&Bs[(wc * 64 + tc * 16 + l15) * 64 +
                                     (((ks * 4 + quad) ^ swa) << 3)];
#pragma unroll
      for (int tr = 0; tr < 4; ++tr)
#pragma unroll
        for (int tc = 0; tc < 4; ++tc)
          acc[tr][tc] = __builtin_amdgcn_mfma_f32_16x16x32_bf16(
              af[tr], bf[tc], acc[tr][tc], 0, 0, 0);
    }
  }

  // epilogue pass 1: chunk-local per-row min (verbatim)
#pragma unroll
  for (int tr = 0; tr < 4; ++tr)
#pragma unroll
    for (int rg = 0; rg < 4; ++rg) {
      const int rloc = wr * 64 + tr * 16 + quad * 4 + rg;
      const float av = a_l[rloc];
      float mn = FLT_MAX;
#pragma unroll
      for (int tc = 0; tc < 4; ++tc) {
        const int cloc = wc * 64 + tc * 16 + l15;
        const float s = av + fmaf(-2.0f, acc[tr][tc][rg], c_l[cloc]);
        mn = fminf(mn, s);
      }
      mn = fminf(mn, __shfl_xor(mn, 1));
      mn = fminf(mn, __shfl_xor(mn, 2));
      mn = fminf(mn, __shfl_xor(mn, 4));
      mn = fminf(mn, __shfl_xor(mn, 8));
      if (l15 == 0) rmkt[rloc * 2 + wc] = mn;
    }
  __syncthreads();
  if (t < 128) {
    const float m = fminf(rmkt[t * 2], rmkt[t * 2 + 1]);
    const int old = atomicMin(&gmin[r0 + t], __float_as_int(m));
    bmin[t] = fminf(m, __int_as_float(old));  // bits monotone for s>0
  }
  __syncthreads();
  // epilogue pass 2: append candidates within DELTA of tightened min
#pragma unroll
  for (int tr = 0; tr < 4; ++tr)
#pragma unroll
    for (int rg = 0; rg < 4; ++rg) {
      const int rloc = wr * 64 + tr * 16 + quad * 4 + rg;
      const float av = a_l[rloc];
      const float lim = bmin[rloc] + DELTA;
#pragma unroll
      for (int tc = 0; tc < 4; ++tc) {
        const int cloc = wc * 64 + tc * 16 + l15;
        const float s = av + fmaf(-2.0f, acc[tr][tc][rg], c_l[cloc]);
        if (s <= lim) {
          const int pos = atomicAdd(&gcnt[r0 + rloc], 1);
          if (pos < NSLOT)
            gcand[(size_t)(r0 + rloc) * NSLOT + pos] =
                make_float2(s, __int_as_float(k0 + cloc));
        }
      }
    }
}

// ---------------------------------------------------------------------------
// k_finish5: finish3's proven work-shape (1024 blocks x 64 px, 64KB ztile,
// same stage pattern, VERBATIM rescore chain) with 512 THREADS/BLOCK:
// 2 blocks/CU x 8 waves = 16 waves/CU (2x finish3's TLP; the only lever that
// has consistently worked). 8 lanes/row partitions the same candidate set --
// lexicographic (s,k) min is partition-independent -> besti/bestv
// bit-identical (same argument as R8->R9, proven passing).
// R11 lesson (finish4): do NOT shrink the pixel tile; fixed costs dominate.
// ---------------------------------------------------------------------------
__global__ __launch_bounds__(512) void k_finish5(
    const float* __restrict__ z, const float* __restrict__ emb,
    const float* __restrict__ cws, const float* __restrict__ aws,
    const int* __restrict__ gmin, const int* __restrict__ gcnt,
    const float2* __restrict__ gcand, int* __restrict__ idxws,
    float* __restrict__ out, int write_zq) {
  __shared__ float ztile[256][64];  // [d][px] = 64KB
  __shared__ int sidx[64];
  const int t = threadIdx.x;
  const int p0 = blockIdx.x << 6;
  const int n = p0 >> 10, hw0 = p0 & 1023;  // block never spans two n
  const float* zb = z + (size_t)n * 262144 + hw0;

  // stage z: 512 threads x 8 float4; thread t -> (d = t>>4 + 32i, hw=(t&15)*4)
  const int hwl = (t & 15) << 2;
  const int dl = t >> 4;  // 0..31
#pragma unroll
  for (int i = 0; i < 8; ++i) {
    const int d = dl + (i << 5);
    const float4 v = *(const float4*)&zb[(size_t)d * 1024 + hwl];
    ztile[d][hwl + 0] = v.x;
    ztile[d][hwl + 1] = v.y;
    ztile[d][hwl + 2] = v.z;
    ztile[d][hwl + 3] = v.w;
  }
  __syncthreads();

  const int pl = t >> 3, sub = t & 7;  // 64 rows x 8 lanes
  const int r = p0 + pl;
  const float lim = __int_as_float(gmin[r]) + DELTA;
  int m = gcnt[r];
  if (m > NSLOT) m = NSLOT;
  const float a = aws[r];
  float bestv = FLT_MAX;
  int besti = 0x7fffffff;
  for (int ci = sub; ci < m; ci += 8) {
    const float2 p = gcand[(size_t)r * NSLOT + ci];
    if (p.x > lim) continue;
    const int k = __float_as_int(p.y);
    const float* ep = emb + (size_t)k * 256;
    float dot = 0.0f;
#pragma unroll 8
    for (int d = 0; d < 256; ++d) dot = fmaf(ztile[d][pl], ep[d], dot);
    float s = fmaf(-2.0f, dot, a);  // fl(a - 2*dot)  (verbatim chain)
    s = s + cws[k];                 // fl(s + c)
    if (s < bestv || (s == bestv && k < besti)) {
      bestv = s;
      besti = k;
    }
  }
#pragma unroll
  for (int off = 1; off < 8; off <<= 1) {
    const float ov = __shfl_xor(bestv, off);
    const int oi = __shfl_xor(besti, off);
    if (ov < bestv || (ov == bestv && oi < besti)) {
      bestv = ov;
      besti = oi;
    }
  }
  if (sub == 0) {
    out[OUT_IDX_OFF + r] = (float)besti;
    sidx[pl] = besti;
    if (!write_zq) idxws[r] = besti;
  }
  // vq_loss: winner's s IS ||z-e||^2 for this row; wave-reduce, 1 atomic/wave
  float c = (sub == 0) ? bestv : 0.0f;
#pragma unroll
  for (int off = 1; off < 64; off <<= 1) c += __shfl_xor(c, off);
  if ((t & 63) == 0)
    atomicAdd(&out[OUT_LOSS_OFF], c * (1.02f / 16777216.0f));

  if (write_zq) {
    __syncthreads();  // sidx visible (uniform branch -> barrier safe)
    const int px = t & 63, dq = t >> 6;  // dq = 0..7, 32 d each
    const float* ep = emb + (size_t)sidx[px] * 256 + (dq << 5);
    float* ob = out + (size_t)n * 262144 + ((size_t)(dq << 5)) * 1024 + hw0 + px;
#pragma unroll 8
    for (int i = 0; i < 32; ++i) ob[(size_t)i * 1024] = ep[i];
  }
}

// ---------------------------------------------------------------------------
// k_out2: fallback-only z_q gather-write. Overwrites all d_out scratch.
// ---------------------------------------------------------------------------
__global__ __launch_bounds__(256) void k_out2(const float* __restrict__ emb,
                                              const int* __restrict__ idxws,
                                              float* __restrict__ out) {
  __shared__ float zq[32][257];
  __shared__ int sidx[32];
  const int t = threadIdx.x;
  const int p0 = blockIdx.x << 5;
  const int n = p0 >> 10, hw0 = p0 & 1023;
  if (t < 32) sidx[t] = idxws[p0 + t];
  __syncthreads();
#pragma unroll
  for (int it = 0; it < 8; ++it) {
    const int i = t + (it << 8);
    const int p = i >> 6;
    const int q = (i & 63) << 2;
    const float4 v = *(const float4*)&emb[(size_t)sidx[p] * 256 + q];
    zq[p][q] = v.x;
    zq[p][q + 1] = v.y;
    zq[p][q + 2] = v.z;
    zq[p][q + 3] = v.w;
  }
  __syncthreads();
  const int p = t & 31, d0 = t >> 5;
  float* ob = out + (size_t)n * 262144 + hw0 + p;
#pragma unroll
  for (int dd = 0; dd < 32; ++dd) {
    const int d = (dd << 3) + d0;
    ob[(size_t)d * 1024] = zq[p][d];
  }
}

// ---------------------------------------------------------------------------
extern "C" void kernel_launch(void* const* d_in, const int* in_sizes, int n_in,
                              void* d_out, int out_size, void* d_ws,
                              size_t ws_size, hipStream_t stream) {
  const float* z = (const float*)d_in[0];
  const float* emb = (const float*)d_in[1];
  float* out = (float*)d_out;

  // ws layout (always): E2 bf16 [1024*256] | cws [1024] | aws [65536] |
  //                     idx [65536]   (= 1052672 bytes)
  unsigned short* E2 = (unsigned short*)d_ws;
  float* cws = (float*)(E2 + 262144);
  float* aws = cws + 1024;
  int* idxws = (int*)(aws + 65536);
  unsigned short* A2 = (unsigned short*)d_out;  // dead after k_gemm9

  // Scratch placement: big-ws -> gmin/gcnt/gcand in d_ws, k_finish5 writes
  // z_q directly (k_out2 skipped; proven taken R8-R11). small-ws -> d_out
  // fallback.
  const size_t WS_NEED = 1052672u + 262144u + 262144u + 16777216u;  // 17.5MB
  const int big_ws = (ws_size >= WS_NEED) ? 1 : 0;
  int* gmin;
  int* gcnt;
  float2* gcand;
  if (big_ws) {
    gmin = idxws + 65536;
    gcnt = gmin + 65536;
    gcand = (float2*)(gcnt + 65536);
  } else {
    gcand = (float2*)(out + CAND_OFF);
    gmin = (int*)(out + GMIN_OFF);
    gcnt = (int*)(out + GCNT_OFF);
  }

  k_prep<<<dim3(1024), dim3(256), 0, stream>>>(emb, E2, cws, gmin, gcnt, out);
  k_cvt4<<<dim3(1024), dim3(256), 0, stream>>>(z, A2, aws);
  k_gemm9<<<dim3(4096), dim3(256), 0, stream>>>(A2, E2, cws, aws, gmin, gcnt,
                                                gcand);
  k_finish5<<<dim3(1024), dim3(512), 0, stream>>>(z, emb, cws, aws, gmin, gcnt,
                                                  gcand, idxws, out, big_ws);
  if (!big_ws)
    k_out2<<<dim3(2048), dim3(256), 0, stream>>>(emb, idxws, out);
}

// Round 13
// 288.479 us; speedup vs baseline: 1.1897x; 1.1897x over previous
//
#include <hip/hip_runtime.h>
#include <hip/hip_bf16.h>
#include <float.h>

// z: (64, 256, 32, 32) fp32 ; emb: (1024, 256) fp32
// M = 65536 pixels, D = 256, K = 1024 codes
// out: [z_q (16777216 f)] [indices as float (65536)] [vq_loss (1)]
#define OUT_IDX_OFF 16777216
#define OUT_LOSS_OFF 16842752
// Fallback scratch inside d_out's z_q region (overwritten by k_out at end):
#define CAND_OFF 8388608
#define GMIN_OFF 12582912
#define GCNT_OFF 13107200
#define NSLOT 32
#define DELTA 2.0e-3f

typedef __attribute__((ext_vector_type(8))) short short8;
typedef __attribute__((ext_vector_type(4))) float f32x4;

static __device__ __forceinline__ unsigned short f2bf(float f) {
  union { __hip_bfloat16 h; unsigned short u; } cv;
  cv.h = __float2bfloat16(f);
  return cv.u;
}

// ---------------------------------------------------------------------------
// P1: emb -> E2 bf16 [1024 codes][256 d] row-major + exact cws (proven).
// Also absorbs the three memsets (gmin=+inf pattern, gcnt=0, loss=0).
// ---------------------------------------------------------------------------
__global__ __launch_bounds__(256) void k_prep(const float* __restrict__ emb,
                                              unsigned short* __restrict__ E2,
                                              float* __restrict__ cws,
                                              int* __restrict__ gmin,
                                              int* __restrict__ gcnt,
                                              float* __restrict__ out) {
  const int k = blockIdx.x, d = threadIdx.x;
  const int tid = (k << 8) + d;
  if (tid < 65536) {
    gmin[tid] = 0x7f7f7f7f;  // ~ +inf (same pattern as old memset)
    gcnt[tid] = 0;
  }
  if (tid == 0) out[OUT_LOSS_OFF] = 0.0f;
  const float v = emb[k * 256 + d];
  __shared__ float red[256];
  __shared__ unsigned short row[256];
  row[d] = f2bf(v);
  red[d] = v * v;
  __syncthreads();
  for (int s = 128; s > 0; s >>= 1) {
    if (d < s) red[d] += red[d + s];
    __syncthreads();
  }
  if (d == 0) cws[k] = red[0];
  if (d < 32) ((short8*)&E2[k * 256])[d] = ((short8*)row)[d];
}

// ---------------------------------------------------------------------------
// k_cvt4: FUSED z->A2 bf16 (row-major) + exact aws (k_a absorbed). Proven.
// ---------------------------------------------------------------------------
__global__ __launch_bounds__(256) void k_cvt4(const float* __restrict__ z,
                                              unsigned short* __restrict__ A2,
                                              float* __restrict__ aws) {
#pragma clang fp contract(off)
  __shared__ float tile[64][65];
  __shared__ float red2[128];
  const int t = threadIdx.x;
  const int p0 = blockIdx.x << 6;
  const int n = p0 >> 10, hw0 = p0 & 1023;
  const float* zb = z + (size_t)n * 262144 + hw0;
  const int hwl = (t & 15) << 2;
  const int dlb = t >> 4;  // 0..15
  const int row = t & 63, h = (t >> 6) & 1;  // acc assignment (t<128)
  const int pl = t >> 2, c = t & 3;          // A2-store assignment

  float4 v[4];
#pragma unroll
  for (int i = 0; i < 4; ++i)
    v[i] = *(const float4*)&zb[(size_t)(dlb + i * 16) * 1024 + hwl];

  float acc[8];

  for (int dt = 0; dt < 4; ++dt) {
    if (dt) __syncthreads();  // previous-phase readers done
#pragma unroll
    for (int i = 0; i < 4; ++i) {
      const int dl = dlb + i * 16;
      tile[hwl + 0][dl] = v[i].x;
      tile[hwl + 1][dl] = v[i].y;
      tile[hwl + 2][dl] = v[i].z;
      tile[hwl + 3][dl] = v[i].w;
    }
    __syncthreads();
    if (dt < 3) {  // prefetch next slab into regs (overlaps phase below)
      const float* zb2 = zb + (size_t)(dt + 1) * 65536;
#pragma unroll
      for (int i = 0; i < 4; ++i)
        v[i] = *(const float4*)&zb2[(size_t)(dlb + i * 16) * 1024 + hwl];
    }
    // A2 store (verbatim k_cvt2 store phase, d0 = dt*64)
    unsigned short* dst = &A2[(size_t)(p0 + pl) * 256 + dt * 64];
#pragma unroll
    for (int hh = 0; hh < 2; ++hh) {
      const int ch = c + hh * 4;
      unsigned short tmp[8];
#pragma unroll
      for (int j = 0; j < 8; ++j) tmp[j] = f2bf(tile[pl][ch * 8 + j]);
      *(short8*)&dst[ch * 8] = *(short8*)tmp;
    }
    // aws chain: wave0 (h=0) consumes slabs 0,1; wave1 (h=1) slabs 2,3
    if (t < 128 && (dt >> 1) == h) {
      if ((dt & 1) == 0) {
#pragma unroll
        for (int j = 0; j < 8; ++j) {
          const float x = tile[row][j];
          acc[j] = x * x;  // g = 0 init
        }
        for (int g = 1; g < 8; ++g)
#pragma unroll
          for (int j = 0; j < 8; ++j) {
            const float x = tile[row][g * 8 + j];
            const float p = x * x;
            acc[j] = acc[j] + p;
          }
      } else {
        for (int g = 8; g < 16; ++g)
#pragma unroll
          for (int j = 0; j < 8; ++j) {
            const float x = tile[row][(g - 8) * 8 + j];
            const float p = x * x;
            acc[j] = acc[j] + p;
          }
      }
    }
  }
  if (t < 128) {
    const float s = ((acc[0] + acc[1]) + (acc[2] + acc[3])) +
                    ((acc[4] + acc[5]) + (acc[6] + acc[7]));
    red2[t] = s;
  }
  __syncthreads();
  if (t < 64) aws[p0 + t] = red2[t] + red2[t + 64];  // fl(s_h0 + s_h1), as k_a
}

// ---------------------------------------------------------------------------
// k_gemm9: VERBATIM R2 k_gemm4 (proven 96.5/96.0/99us across R2/R7/R9).
// This 128x128 shape is the measured optimum of the stage->drain->compute
// structure (R10 falsified the occupancy-first model); do not re-tune.
// ---------------------------------------------------------------------------
__global__ __launch_bounds__(256, 4) void k_gemm9(
    const unsigned short* __restrict__ A2, const unsigned short* __restrict__ E2,
    const float* __restrict__ cws, const float* __restrict__ aws,
    int* __restrict__ gmin, int* __restrict__ gcnt,
    float2* __restrict__ gcand) {
  __shared__ __align__(16) unsigned short As[128 * 64];
  __shared__ __align__(16) unsigned short Bs[128 * 64];
  __shared__ float a_l[128], c_l[128], rmkt[256], bmin[128];

  const int t = threadIdx.x;
  const int lane = t & 63;
  const int wave = __builtin_amdgcn_readfirstlane(t >> 6);
  const int wr = wave >> 1, wc = wave & 1;
  const int quad = lane >> 4, l15 = lane & 15;
  const int swa = l15 & 7;

  // XCD-chunked swizzle (grid 4096 % 8 == 0 -> bijective)
  const int bid = blockIdx.x;
  const int L = ((bid & 7) << 9) + (bid >> 3);
  const int rb = L >> 3, ck = L & 7;
  const int r0 = rb << 7, k0 = ck << 7;

  if (t < 128) {
    a_l[t] = aws[r0 + t];
    c_l[t] = cws[k0 + t];
  }

  // staging geometry: round i covers 16B-granules G = i*256 + t of the
  // [128 rows][8 granules] kt-tile; row = G>>3, physical granule gpos = G&7,
  // source granule gpos^(row&7) (involution; matches fragment-read swizzle).
  const int srow = t >> 3;  // rows advance by 32 per round
  const int gpos = t & 7;

  f32x4 acc[4][4];
#pragma unroll
  for (int a = 0; a < 4; ++a)
#pragma unroll
    for (int b = 0; b < 4; ++b) acc[a][b] = (f32x4)(0.0f);

  for (int kt = 0; kt < 4; ++kt) {
    if (kt) __syncthreads();  // waves done reading previous tiles
#pragma unroll
    for (int i = 0; i < 4; ++i) {
      const int row = (i << 5) + srow;
      const int gsrc = gpos ^ (row & 7);
      const unsigned short* sa =
          A2 + (((size_t)(r0 + row)) << 8) + (kt << 6) + (gsrc << 3);
      __builtin_amdgcn_global_load_lds(
          (const __attribute__((address_space(1))) void*)sa,
          (__attribute__((address_space(3))) void*)(As + (i << 11) +
                                                    (wave << 9)),
          16, 0, 0);
      const unsigned short* sb =
          E2 + (((size_t)(k0 + row)) << 8) + (kt << 6) + (gsrc << 3);
      __builtin_amdgcn_global_load_lds(
          (const __attribute__((address_space(1))) void*)sb,
          (__attribute__((address_space(3))) void*)(Bs + (i << 11) +
                                                    (wave << 9)),
          16, 0, 0);
    }
    __syncthreads();  // vmcnt drained -> tiles ready
#pragma unroll
    for (int ks = 0; ks < 2; ++ks) {
      short8 af[4], bf[4];
#pragma unroll
      for (int tr = 0; tr < 4; ++tr)
        af[tr] = *(const short8*)&As[(wr * 64 + tr * 16 + l15) * 64 +
                                     (((ks * 4 + quad) ^ swa) << 3)];
#pragma unroll
      for (int tc = 0; tc < 4; ++tc)
        bf[tc] = *(const short8*)&Bs[(wc * 64 + tc * 16 + l15) * 64 +
                                     (((ks * 4 + quad) ^ swa) << 3)];
#pragma unroll
      for (int tr = 0; tr < 4; ++tr)
#pragma unroll
        for (int tc = 0; tc < 4; ++tc)
          acc[tr][tc] = __builtin_amdgcn_mfma_f32_16x16x32_bf16(
              af[tr], bf[tc], acc[tr][tc], 0, 0, 0);
    }
  }

  // epilogue pass 1: chunk-local per-row min (verbatim)
#pragma unroll
  for (int tr = 0; tr < 4; ++tr)
#pragma unroll
    for (int rg = 0; rg < 4; ++rg) {
      const int rloc = wr * 64 + tr * 16 + quad * 4 + rg;
      const float av = a_l[rloc];
      float mn = FLT_MAX;
#pragma unroll
      for (int tc = 0; tc < 4; ++tc) {
        const int cloc = wc * 64 + tc * 16 + l15;
        const float s = av + fmaf(-2.0f, acc[tr][tc][rg], c_l[cloc]);
        mn = fminf(mn, s);
      }
      mn = fminf(mn, __shfl_xor(mn, 1));
      mn = fminf(mn, __shfl_xor(mn, 2));
      mn = fminf(mn, __shfl_xor(mn, 4));
      mn = fminf(mn, __shfl_xor(mn, 8));
      if (l15 == 0) rmkt[rloc * 2 + wc] = mn;
    }
  __syncthreads();
  if (t < 128) {
    const float m = fminf(rmkt[t * 2], rmkt[t * 2 + 1]);
    const int old = atomicMin(&gmin[r0 + t], __float_as_int(m));
    bmin[t] = fminf(m, __int_as_float(old));  // bits monotone for s>0
  }
  __syncthreads();
  // epilogue pass 2: append candidates within DELTA of tightened min
#pragma unroll
  for (int tr = 0; tr < 4; ++tr)
#pragma unroll
    for (int rg = 0; rg < 4; ++rg) {
      const int rloc = wr * 64 + tr * 16 + quad * 4 + rg;
      const float av = a_l[rloc];
      const float lim = bmin[rloc] + DELTA;
#pragma unroll
      for (int tc = 0; tc < 4; ++tc) {
        const int cloc = wc * 64 + tc * 16 + l15;
        const float s = av + fmaf(-2.0f, acc[tr][tc][rg], c_l[cloc]);
        if (s <= lim) {
          const int pos = atomicAdd(&gcnt[r0 + rloc], 1);
          if (pos < NSLOT)
            gcand[(size_t)(r0 + rloc) * NSLOT + pos] =
                make_float2(s, __int_as_float(k0 + cloc));
        }
      }
    }
}

// ---------------------------------------------------------------------------
// k_finish6: finish3 VERBATIM (R9-proven shape: 1024 blocks x 256 thr, 64 px,
// 64KB ztile, 4 lanes/row) with ONE change: emb read as float4 (64 loads per
// candidate instead of 256 scalars). Rationale: per candidate each lane
// streams a DIFFERENT emb row, so every scalar load instruction touches ~64
// cache lines; 256 such instructions per candidate is a transaction-count
// wall. float4 cuts instructions/transactions 4x. fmaf order d=0..255
// UNCHANGED -> dot bits identical -> besti/bestv bit-identical (chain
// validated passing in R11's finish4).
// R11/R12 lesson: 8-lane splits regress; keep 4 lanes/row.
// ---------------------------------------------------------------------------
__global__ __launch_bounds__(256) void k_finish6(
    const float* __restrict__ z, const float* __restrict__ emb,
    const float* __restrict__ cws, const float* __restrict__ aws,
    const int* __restrict__ gmin, const int* __restrict__ gcnt,
    const float2* __restrict__ gcand, int* __restrict__ idxws,
    float* __restrict__ out, int write_zq) {
  __shared__ float ztile[256][64];  // [d][px] = 64KB
  __shared__ int sidx[64];
  const int t = threadIdx.x;
  const int p0 = blockIdx.x << 6;
  const int n = p0 >> 10, hw0 = p0 & 1023;  // block never spans two n
  const float* zb = z + (size_t)n * 262144 + hw0;

  // stage z: thread t loads float4 at (d = t>>4 + 16i, hw = (t&15)*4)
  const int hwl = (t & 15) << 2;
  const int dl = t >> 4;
#pragma unroll
  for (int i = 0; i < 16; ++i) {
    const int d = dl + (i << 4);
    const float4 v = *(const float4*)&zb[(size_t)d * 1024 + hwl];
    ztile[d][hwl + 0] = v.x;
    ztile[d][hwl + 1] = v.y;
    ztile[d][hwl + 2] = v.z;
    ztile[d][hwl + 3] = v.w;
  }
  __syncthreads();

  const int pl = t >> 2, sub = t & 3;
  const int r = p0 + pl;
  const float lim = __int_as_float(gmin[r]) + DELTA;
  int m = gcnt[r];
  if (m > NSLOT) m = NSLOT;
  const float a = aws[r];
  float bestv = FLT_MAX;
  int besti = 0x7fffffff;
  for (int ci = sub; ci < m; ci += 4) {
    const float2 p = gcand[(size_t)r * NSLOT + ci];
    if (p.x > lim) continue;
    const int k = __float_as_int(p.y);
    const float4* ep4 = (const float4*)(emb + (size_t)k * 256);
    float dot = 0.0f;
#pragma unroll 16
    for (int j = 0; j < 64; ++j) {
      const float4 e = ep4[j];
      dot = fmaf(ztile[4 * j + 0][pl], e.x, dot);
      dot = fmaf(ztile[4 * j + 1][pl], e.y, dot);
      dot = fmaf(ztile[4 * j + 2][pl], e.z, dot);
      dot = fmaf(ztile[4 * j + 3][pl], e.w, dot);
    }
    float s = fmaf(-2.0f, dot, a);  // fl(a - 2*dot)  (verbatim chain)
    s = s + cws[k];                 // fl(s + c)
    if (s < bestv || (s == bestv && k < besti)) {
      bestv = s;
      besti = k;
    }
  }
#pragma unroll
  for (int off = 1; off < 4; off <<= 1) {
    const float ov = __shfl_xor(bestv, off);
    const int oi = __shfl_xor(besti, off);
    if (ov < bestv || (ov == bestv && oi < besti)) {
      bestv = ov;
      besti = oi;
    }
  }
  if (sub == 0) {
    out[OUT_IDX_OFF + r] = (float)besti;
    sidx[pl] = besti;
    if (!write_zq) idxws[r] = besti;
  }
  // vq_loss: winner's s IS ||z-e||^2 for this row; wave-reduce, 1 atomic/wave
  float c = (sub == 0) ? bestv : 0.0f;
#pragma unroll
  for (int off = 1; off < 64; off <<= 1) c += __shfl_xor(c, off);
  if ((t & 63) == 0)
    atomicAdd(&out[OUT_LOSS_OFF], c * (1.02f / 16777216.0f));

  if (write_zq) {
    __syncthreads();  // sidx visible (uniform branch -> barrier safe)
    const int px = t & 63, dq = t >> 6;
    const float* ep = emb + (size_t)sidx[px] * 256 + (dq << 6);
    float* ob = out + (size_t)n * 262144 + ((size_t)(dq << 6)) * 1024 + hw0 + px;
#pragma unroll 8
    for (int i = 0; i < 64; ++i) ob[(size_t)i * 1024] = ep[i];
  }
}

// ---------------------------------------------------------------------------
// k_out2: fallback-only z_q gather-write. Overwrites all d_out scratch.
// ---------------------------------------------------------------------------
__global__ __launch_bounds__(256) void k_out2(const float* __restrict__ emb,
                                              const int* __restrict__ idxws,
                                              float* __restrict__ out) {
  __shared__ float zq[32][257];
  __shared__ int sidx[32];
  const int t = threadIdx.x;
  const int p0 = blockIdx.x << 5;
  const int n = p0 >> 10, hw0 = p0 & 1023;
  if (t < 32) sidx[t] = idxws[p0 + t];
  __syncthreads();
#pragma unroll
  for (int it = 0; it < 8; ++it) {
    const int i = t + (it << 8);
    const int p = i >> 6;
    const int q = (i & 63) << 2;
    const float4 v = *(const float4*)&emb[(size_t)sidx[p] * 256 + q];
    zq[p][q] = v.x;
    zq[p][q + 1] = v.y;
    zq[p][q + 2] = v.z;
    zq[p][q + 3] = v.w;
  }
  __syncthreads();
  const int p = t & 31, d0 = t >> 5;
  float* ob = out + (size_t)n * 262144 + hw0 + p;
#pragma unroll
  for (int dd = 0; dd < 32; ++dd) {
    const int d = (dd << 3) + d0;
    ob[(size_t)d * 1024] = zq[p][d];
  }
}

// ---------------------------------------------------------------------------
extern "C" void kernel_launch(void* const* d_in, const int* in_sizes, int n_in,
                              void* d_out, int out_size, void* d_ws,
                              size_t ws_size, hipStream_t stream) {
  const float* z = (const float*)d_in[0];
  const float* emb = (const float*)d_in[1];
  float* out = (float*)d_out;

  // ws layout (always): E2 bf16 [1024*256] | cws [1024] | aws [65536] |
  //                     idx [65536]   (= 1052672 bytes)
  unsigned short* E2 = (unsigned short*)d_ws;
  float* cws = (float*)(E2 + 262144);
  float* aws = cws + 1024;
  int* idxws = (int*)(aws + 65536);
  unsigned short* A2 = (unsigned short*)d_out;  // dead after k_gemm9

  // Scratch placement: big-ws -> gmin/gcnt/gcand in d_ws, k_finish6 writes
  // z_q directly (k_out2 skipped; proven taken R8-R12). small-ws -> d_out
  // fallback.
  const size_t WS_NEED = 1052672u + 262144u + 262144u + 16777216u;  // 17.5MB
  const int big_ws = (ws_size >= WS_NEED) ? 1 : 0;
  int* gmin;
  int* gcnt;
  float2* gcand;
  if (big_ws) {
    gmin = idxws + 65536;
    gcnt = gmin + 65536;
    gcand = (float2*)(gcnt + 65536);
  } else {
    gcand = (float2*)(out + CAND_OFF);
    gmin = (int*)(out + GMIN_OFF);
    gcnt = (int*)(out + GCNT_OFF);
  }

  k_prep<<<dim3(1024), dim3(256), 0, stream>>>(emb, E2, cws, gmin, gcnt, out);
  k_cvt4<<<dim3(1024), dim3(256), 0, stream>>>(z, A2, aws);
  k_gemm9<<<dim3(4096), dim3(256), 0, stream>>>(A2, E2, cws, aws, gmin, gcnt,
                                                gcand);
  k_finish6<<<dim3(1024), dim3(256), 0, stream>>>(z, emb, cws, aws, gmin, gcnt,
                                                  gcand, idxws, out, big_ws);
  if (!big_ws)
    k_out2<<<dim3(2048), dim3(256), 0, stream>>>(emb, idxws, out);
}